// Round 2
// baseline (248.834 us; speedup 1.0000x reference)
//
#include <hip/hip_runtime.h>
#include <cstdint>
#include <cstddef>

// Problem constants (fixed by the reference: N=4096, D=512)
constexpr int N_ROWS = 4096;
constexpr int D      = 512;
constexpr int M      = 8192;   // 2N
constexpr int NTILE  = 64;     // M / 128
constexpr int NBLK   = NTILE * (NTILE + 1) / 2;   // 2080 upper-tri tile pairs

using f32x4  = __attribute__((ext_vector_type(4))) float;
using bf16x8 = __attribute__((ext_vector_type(8))) __bf16;
using us8    = __attribute__((ext_vector_type(8))) unsigned short;

// RNE float -> bf16 (inputs are finite, no NaN handling needed)
__device__ inline unsigned short f2bf(float f) {
    unsigned int u = __float_as_uint(f);
    u += 0x7fffu + ((u >> 16) & 1u);
    return (unsigned short)(u >> 16);
}
__device__ inline float bf2f(unsigned short s) {
    return __uint_as_float(((unsigned int)s) << 16);
}

// 16B async global->LDS copy. LDS dest must be wave-uniform base; HW writes
// lane l at base + l*16.
#define ASYNC_CP16(gsrc, ldst)                                                      \
    __builtin_amdgcn_global_load_lds(                                               \
        (const __attribute__((address_space(1))) unsigned int*)(gsrc),              \
        (__attribute__((address_space(3))) unsigned int*)(ldst), 16, 0, 0)

// ---------------------------------------------------------------------------
// Kernel 1: fused normalize + positive-pair logits.
// One wave handles PAIR k: row k (emb_i) and row k+N (emb_j).
//  - L2-normalize both rows -> bf16 Z in ws
//  - diag sumsq of the bf16-rounded rows (what the MFMA diagonal computes)
//  - pos[k] = 2 * dot(emb_i[k], emb_j[k]) * inv_i * inv_j   (fp32 exact path)
//  - zero rowsum for both rows; block 0 zeroes the completion counter
// ---------------------------------------------------------------------------
__global__ __launch_bounds__(256) void normpos_kernel(
    const float* __restrict__ emb_i, const float* __restrict__ emb_j,
    unsigned short* __restrict__ zb, float* __restrict__ rowsum,
    float* __restrict__ diagss, float* __restrict__ pos,
    unsigned int* __restrict__ donecnt)
{
    const int wave = threadIdx.x >> 6, lane = threadIdx.x & 63;
    const int k = blockIdx.x * 4 + wave;
    if (blockIdx.x == 0 && threadIdx.x == 0) *donecnt = 0u;

    const float4* a = (const float4*)(emb_i + (size_t)k * D);
    const float4* b = (const float4*)(emb_j + (size_t)k * D);
    float4 a0 = a[lane * 2], a1 = a[lane * 2 + 1];
    float4 b0 = b[lane * 2], b1 = b[lane * 2 + 1];

    float ssi = a0.x*a0.x + a0.y*a0.y + a0.z*a0.z + a0.w*a0.w
              + a1.x*a1.x + a1.y*a1.y + a1.z*a1.z + a1.w*a1.w;
    float ssj = b0.x*b0.x + b0.y*b0.y + b0.z*b0.z + b0.w*b0.w
              + b1.x*b1.x + b1.y*b1.y + b1.z*b1.z + b1.w*b1.w;
    float dp  = a0.x*b0.x + a0.y*b0.y + a0.z*b0.z + a0.w*b0.w
              + a1.x*b1.x + a1.y*b1.y + a1.z*b1.z + a1.w*b1.w;
    #pragma unroll
    for (int off = 32; off; off >>= 1) {
        ssi += __shfl_xor(ssi, off, 64);
        ssj += __shfl_xor(ssj, off, 64);
        dp  += __shfl_xor(dp,  off, 64);
    }
    const float invi = rsqrtf(ssi), invj = rsqrtf(ssj);

    const float zi[8] = {a0.x*invi, a0.y*invi, a0.z*invi, a0.w*invi,
                         a1.x*invi, a1.y*invi, a1.z*invi, a1.w*invi};
    const float zj[8] = {b0.x*invj, b0.y*invj, b0.z*invj, b0.w*invj,
                         b1.x*invj, b1.y*invj, b1.z*invj, b1.w*invj};
    us8 pi, pj;
    float dssi = 0.f, dssj = 0.f;
    #pragma unroll
    for (int t = 0; t < 8; ++t) {
        unsigned short bi = f2bf(zi[t]), bj = f2bf(zj[t]);
        pi[t] = bi; pj[t] = bj;
        float fi = bf2f(bi), fj = bf2f(bj);
        dssi += fi * fi; dssj += fj * fj;
    }
    *(us8*)(zb + (size_t)k * D + lane * 8)            = pi;
    *(us8*)(zb + (size_t)(k + N_ROWS) * D + lane * 8) = pj;
    #pragma unroll
    for (int off = 32; off; off >>= 1) {
        dssi += __shfl_xor(dssi, off, 64);
        dssj += __shfl_xor(dssj, off, 64);
    }
    if (lane == 0) {
        rowsum[k]          = 0.0f;
        rowsum[k + N_ROWS] = 0.0f;
        diagss[k]          = dssi;
        diagss[k + N_ROWS] = dssj;
        pos[k]             = 2.0f * dp * invi * invj;
    }
}

// ---------------------------------------------------------------------------
// Kernel 2: symmetric fused sim-GEMM + exp + row/col sums + finalize.
// Upper-triangle tile pairs only (bi <= bj): 2080 blocks of a 64x64 tile grid.
// Off-diagonal blocks add row sums (tile bi rows) AND column sums (tile bj
// rows, by symmetry). Last finished block computes the scalar loss.
// 128x128 tile, 4 waves 2x2, BK=32, mfma_f32_16x16x32_bf16, 16B
// global_load_lds with XOR chunk swizzle (2-way aliasing = free).
// ---------------------------------------------------------------------------
__global__ __launch_bounds__(256, 3) void simgemm_kernel(
    const unsigned short* __restrict__ zb, float* __restrict__ rowsum,
    const float* __restrict__ diagss, const float* __restrict__ pos,
    unsigned int* __restrict__ donecnt, float* __restrict__ out)
{
    __shared__ unsigned short As[128 * 32];
    __shared__ unsigned short Bs[128 * 32];
    const int tid  = threadIdx.x;
    const int wave = tid >> 6, lane = tid & 63;
    const int l15  = lane & 15, ks = lane >> 4;

    // Decode linear block id -> (bi, bj), bi <= bj. cum(bi) = bi*(129-bi)/2.
    const int t = blockIdx.x;
    int bi = (int)((129.0f - sqrtf(129.0f * 129.0f - 8.0f * (float)t)) * 0.5f);
    while (bi > 0 && bi * (129 - bi) / 2 > t) --bi;
    while ((bi + 1) * (129 - (bi + 1)) / 2 <= t) ++bi;
    const int bj = bi + (t - bi * (129 - bi) / 2);
    const bool diag = (bi == bj);

    const int wrow = (wave >> 1) * 64, wcol = (wave & 1) * 64;

    // Staging mapping: tile = 8 chunks of 1024B (16 rows each); wave w owns
    // chunks {2w, 2w+1}. lane l -> row chunk*16 + (l>>2), phys 16B slot l&3.
    const int ch0 = wave * 2;
    const int sr0 = ch0 * 16 + (lane >> 2);
    const int sc  = ((lane & 3) ^ ((sr0 >> 1) & 3)) * 8;   // swizzled k-offset (elems)
    const unsigned short* gA0 = zb + (size_t)(bi * 128 + sr0) * D + sc;
    const unsigned short* gB0 = zb + (size_t)(bj * 128 + sr0) * D + sc;
    unsigned short* lA0 = As + ch0 * 512;
    unsigned short* lA1 = As + ch0 * 512 + 512;
    unsigned short* lB0 = Bs + ch0 * 512;
    unsigned short* lB1 = Bs + ch0 * 512 + 512;

    f32x4 acc[4][4] = {};
    const int swOff = (ks ^ ((l15 >> 1) & 3)) * 8;  // swizzled frag k-offset (elems)

    for (int kc = 0; kc < D; kc += 32) {
        ASYNC_CP16(gA0 + kc,          lA0);
        ASYNC_CP16(gA0 + kc + 16 * D, lA1);
        ASYNC_CP16(gB0 + kc,          lB0);
        ASYNC_CP16(gB0 + kc + 16 * D, lB1);
        __syncthreads();

        bf16x8 af[4], bg[4];
        #pragma unroll
        for (int f = 0; f < 4; ++f) {
            af[f] = *(const bf16x8*)(As + (wrow + f * 16 + l15) * 32 + swOff);
            bg[f] = *(const bf16x8*)(Bs + (wcol + f * 16 + l15) * 32 + swOff);
        }
        #pragma unroll
        for (int i = 0; i < 4; ++i)
            #pragma unroll
            for (int j = 0; j < 4; ++j)
                acc[i][j] = __builtin_amdgcn_mfma_f32_16x16x32_bf16(
                    af[i], bg[j], acc[i][j], 0, 0, 0);
        __syncthreads();
    }

    // Epilogue. C/D layout: row = ks*4 + r, col = l15 (within each 16x16).
    // e = exp(sim/T) = exp(2*acc). Each e feeds the row-partial (reduce over
    // j and l15) and, for off-diag blocks, the col-partial (reduce over i, r,
    // ks) — computed once from registers.
    float rowp[4][4] = {};
    float* rsA = rowsum + bi * 128 + wrow;
    float* rsB = rowsum + bj * 128 + wcol;
    #pragma unroll
    for (int j = 0; j < 4; ++j) {
        float cp = 0.f;
        #pragma unroll
        for (int i = 0; i < 4; ++i)
            #pragma unroll
            for (int r = 0; r < 4; ++r) {
                float e = __expf(2.0f * acc[i][j][r]);
                rowp[i][r] += e;
                cp += e;
            }
        if (!diag) {
            cp += __shfl_xor(cp, 16, 64);
            cp += __shfl_xor(cp, 32, 64);
            if (ks == 0) atomicAdd(rsB + j * 16 + l15, cp);
        }
    }
    #pragma unroll
    for (int i = 0; i < 4; ++i)
        #pragma unroll
        for (int r = 0; r < 4; ++r) {
            float e = rowp[i][r];
            e += __shfl_xor(e, 1, 64);
            e += __shfl_xor(e, 2, 64);
            e += __shfl_xor(e, 4, 64);
            e += __shfl_xor(e, 8, 64);
            if (l15 == 0) atomicAdd(rsA + i * 16 + ks * 4 + r, e);
        }

    // ---- completion-counter finalize (last block only) ----
    __shared__ bool isLast;
    __threadfence();
    __syncthreads();
    if (tid == 0) {
        unsigned int old = atomicAdd(donecnt, 1u);
        isLast = (old == (unsigned int)(NBLK - 1));
    }
    __syncthreads();
    if (!isLast) return;
    __threadfence();

    float local = 0.f;
    for (int i = tid; i < M; i += 256) {
        float rs = __hip_atomic_load(rowsum + i, __ATOMIC_RELAXED,
                                     __HIP_MEMORY_SCOPE_AGENT);
        local += __logf(rs - __expf(2.0f * diagss[i]));
    }
    for (int k = tid; k < N_ROWS; k += 256)
        local -= 2.0f * pos[k];
    #pragma unroll
    for (int off = 32; off; off >>= 1) local += __shfl_xor(local, off, 64);
    __shared__ float red[4];
    if (lane == 0) red[wave] = local;
    __syncthreads();
    if (tid == 0)
        out[0] = (red[0] + red[1] + red[2] + red[3]) * (1.0f / 8192.0f);
}

// ---------------------------------------------------------------------------
extern "C" void kernel_launch(void* const* d_in, const int* in_sizes, int n_in,
                              void* d_out, int out_size, void* d_ws, size_t ws_size,
                              hipStream_t stream)
{
    const float* emb_i = (const float*)d_in[0];
    const float* emb_j = (const float*)d_in[1];

    // ws layout: zb bf16 [M][D] (8 MB) | rowsum f32[M] | diagss f32[M]
    //            | pos f32[N] | donecnt u32   (~8.4 MB total)
    unsigned short* zb = (unsigned short*)d_ws;
    float* rowsum = (float*)((char*)d_ws + (size_t)M * D * sizeof(unsigned short));
    float* diagss = rowsum + M;
    float* pos    = diagss + M;
    unsigned int* donecnt = (unsigned int*)(pos + N_ROWS);
    float* out    = (float*)d_out;

    normpos_kernel<<<N_ROWS / 4, 256, 0, stream>>>(emb_i, emb_j, zb, rowsum,
                                                   diagss, pos, donecnt);
    simgemm_kernel<<<NBLK, 256, 0, stream>>>(zb, rowsum, diagss, pos,
                                             donecnt, out);
}

// Round 3
// 139.924 us; speedup vs baseline: 1.7783x; 1.7783x over previous
//
#include <hip/hip_runtime.h>
#include <cstdint>
#include <cstddef>

// Problem constants (fixed by the reference: N=4096, D=512)
constexpr int N_ROWS = 4096;
constexpr int D      = 512;
constexpr int M      = 8192;   // 2N
constexpr int NTILE  = 64;     // M / 128
constexpr int NBLK   = NTILE * (NTILE + 1) / 2;   // 2080 upper-tri tile pairs

using f32x4  = __attribute__((ext_vector_type(4))) float;
using bf16x8 = __attribute__((ext_vector_type(8))) __bf16;
using us8    = __attribute__((ext_vector_type(8))) unsigned short;

// RNE float -> bf16 (inputs are finite, no NaN handling needed)
__device__ inline unsigned short f2bf(float f) {
    unsigned int u = __float_as_uint(f);
    u += 0x7fffu + ((u >> 16) & 1u);
    return (unsigned short)(u >> 16);
}
__device__ inline float bf2f(unsigned short s) {
    return __uint_as_float(((unsigned int)s) << 16);
}

// 16B async global->LDS copy. LDS dest must be wave-uniform base; HW writes
// lane l at base + l*16.
#define ASYNC_CP16(gsrc, ldst)                                                      \
    __builtin_amdgcn_global_load_lds(                                               \
        (const __attribute__((address_space(1))) unsigned int*)(gsrc),              \
        (__attribute__((address_space(3))) unsigned int*)(ldst), 16, 0, 0)

// ---------------------------------------------------------------------------
// Kernel 1: fused normalize + positive-pair logits.
// One wave handles PAIR k: row k (emb_i) and row k+N (emb_j).
//  - L2-normalize both rows -> bf16 Z in ws
//  - diag sumsq of the bf16-rounded rows (what the MFMA diagonal computes)
//  - pos[k] = 2 * dot(emb_i[k], emb_j[k]) * inv_i * inv_j   (fp32 exact path)
//  - zero rowsum for both rows (ws is poisoned 0xAA before every timed launch)
// ---------------------------------------------------------------------------
__global__ __launch_bounds__(256) void normpos_kernel(
    const float* __restrict__ emb_i, const float* __restrict__ emb_j,
    unsigned short* __restrict__ zb, float* __restrict__ rowsum,
    float* __restrict__ diagss, float* __restrict__ pos)
{
    const int wave = threadIdx.x >> 6, lane = threadIdx.x & 63;
    const int k = blockIdx.x * 4 + wave;

    const float4* a = (const float4*)(emb_i + (size_t)k * D);
    const float4* b = (const float4*)(emb_j + (size_t)k * D);
    float4 a0 = a[lane * 2], a1 = a[lane * 2 + 1];
    float4 b0 = b[lane * 2], b1 = b[lane * 2 + 1];

    float ssi = a0.x*a0.x + a0.y*a0.y + a0.z*a0.z + a0.w*a0.w
              + a1.x*a1.x + a1.y*a1.y + a1.z*a1.z + a1.w*a1.w;
    float ssj = b0.x*b0.x + b0.y*b0.y + b0.z*b0.z + b0.w*b0.w
              + b1.x*b1.x + b1.y*b1.y + b1.z*b1.z + b1.w*b1.w;
    float dp  = a0.x*b0.x + a0.y*b0.y + a0.z*b0.z + a0.w*b0.w
              + a1.x*b1.x + a1.y*b1.y + a1.z*b1.z + a1.w*b1.w;
    #pragma unroll
    for (int off = 32; off; off >>= 1) {
        ssi += __shfl_xor(ssi, off, 64);
        ssj += __shfl_xor(ssj, off, 64);
        dp  += __shfl_xor(dp,  off, 64);
    }
    const float invi = rsqrtf(ssi), invj = rsqrtf(ssj);

    const float zi[8] = {a0.x*invi, a0.y*invi, a0.z*invi, a0.w*invi,
                         a1.x*invi, a1.y*invi, a1.z*invi, a1.w*invi};
    const float zj[8] = {b0.x*invj, b0.y*invj, b0.z*invj, b0.w*invj,
                         b1.x*invj, b1.y*invj, b1.z*invj, b1.w*invj};
    us8 pi, pj;
    float dssi = 0.f, dssj = 0.f;
    #pragma unroll
    for (int t = 0; t < 8; ++t) {
        unsigned short bi = f2bf(zi[t]), bj = f2bf(zj[t]);
        pi[t] = bi; pj[t] = bj;
        float fi = bf2f(bi), fj = bf2f(bj);
        dssi += fi * fi; dssj += fj * fj;
    }
    *(us8*)(zb + (size_t)k * D + lane * 8)            = pi;
    *(us8*)(zb + (size_t)(k + N_ROWS) * D + lane * 8) = pj;
    #pragma unroll
    for (int off = 32; off; off >>= 1) {
        dssi += __shfl_xor(dssi, off, 64);
        dssj += __shfl_xor(dssj, off, 64);
    }
    if (lane == 0) {
        rowsum[k]          = 0.0f;
        rowsum[k + N_ROWS] = 0.0f;
        diagss[k]          = dssi;
        diagss[k + N_ROWS] = dssj;
        pos[k]             = 2.0f * dp * invi * invj;
    }
}

// ---------------------------------------------------------------------------
// Kernel 2: symmetric fused sim-GEMM + exp + row/col sums.
// Upper-triangle tile pairs only (bi <= bj): 2080 blocks of a 64x64 tile grid.
// Off-diagonal blocks add row sums (tile bi rows) AND column sums (tile bj
// rows, by symmetry). NO fences (device-scope fences thrash per-XCD L2 —
// round-2 regression: FETCH 33->75MB, MfmaUtil 29->7%).
// 128x128 tile, 4 waves 2x2, BK=32, mfma_f32_16x16x32_bf16, 16B
// global_load_lds with XOR chunk swizzle (2-way aliasing = free).
// ---------------------------------------------------------------------------
__global__ __launch_bounds__(256, 3) void simgemm_kernel(
    const unsigned short* __restrict__ zb, float* __restrict__ rowsum)
{
    __shared__ unsigned short As[128 * 32];
    __shared__ unsigned short Bs[128 * 32];
    const int tid  = threadIdx.x;
    const int wave = tid >> 6, lane = tid & 63;
    const int l15  = lane & 15, ks = lane >> 4;

    // Decode linear block id -> (bi, bj), bi <= bj. cum(bi) = bi*(129-bi)/2.
    const int t = blockIdx.x;
    int bi = (int)((129.0f - sqrtf(129.0f * 129.0f - 8.0f * (float)t)) * 0.5f);
    while (bi > 0 && bi * (129 - bi) / 2 > t) --bi;
    while ((bi + 1) * (129 - (bi + 1)) / 2 <= t) ++bi;
    const int bj = bi + (t - bi * (129 - bi) / 2);
    const bool diag = (bi == bj);

    const int wrow = (wave >> 1) * 64, wcol = (wave & 1) * 64;

    // Staging mapping: tile = 8 chunks of 1024B (16 rows each); wave w owns
    // chunks {2w, 2w+1}. lane l -> row chunk*16 + (l>>2), phys 16B slot l&3.
    const int ch0 = wave * 2;
    const int sr0 = ch0 * 16 + (lane >> 2);
    const int sc  = ((lane & 3) ^ ((sr0 >> 1) & 3)) * 8;   // swizzled k-offset (elems)
    const unsigned short* gA0 = zb + (size_t)(bi * 128 + sr0) * D + sc;
    const unsigned short* gB0 = zb + (size_t)(bj * 128 + sr0) * D + sc;
    unsigned short* lA0 = As + ch0 * 512;
    unsigned short* lA1 = As + ch0 * 512 + 512;
    unsigned short* lB0 = Bs + ch0 * 512;
    unsigned short* lB1 = Bs + ch0 * 512 + 512;

    f32x4 acc[4][4] = {};
    const int swOff = (ks ^ ((l15 >> 1) & 3)) * 8;  // swizzled frag k-offset (elems)

    for (int kc = 0; kc < D; kc += 32) {
        ASYNC_CP16(gA0 + kc,          lA0);
        ASYNC_CP16(gA0 + kc + 16 * D, lA1);
        ASYNC_CP16(gB0 + kc,          lB0);
        ASYNC_CP16(gB0 + kc + 16 * D, lB1);
        __syncthreads();

        bf16x8 af[4], bg[4];
        #pragma unroll
        for (int f = 0; f < 4; ++f) {
            af[f] = *(const bf16x8*)(As + (wrow + f * 16 + l15) * 32 + swOff);
            bg[f] = *(const bf16x8*)(Bs + (wcol + f * 16 + l15) * 32 + swOff);
        }
        #pragma unroll
        for (int i = 0; i < 4; ++i)
            #pragma unroll
            for (int j = 0; j < 4; ++j)
                acc[i][j] = __builtin_amdgcn_mfma_f32_16x16x32_bf16(
                    af[i], bg[j], acc[i][j], 0, 0, 0);
        __syncthreads();
    }

    // Epilogue. C/D layout: row = ks*4 + r, col = l15 (within each 16x16).
    // e = exp(sim/T) = exp(2*acc). Each e feeds the row-partial (reduce over
    // j and l15) and, for off-diag blocks, the col-partial (reduce over i, r,
    // ks) — computed once from registers.
    float rowp[4][4] = {};
    float* rsA = rowsum + bi * 128 + wrow;
    float* rsB = rowsum + bj * 128 + wcol;
    #pragma unroll
    for (int j = 0; j < 4; ++j) {
        float cp = 0.f;
        #pragma unroll
        for (int i = 0; i < 4; ++i)
            #pragma unroll
            for (int r = 0; r < 4; ++r) {
                float e = __expf(2.0f * acc[i][j][r]);
                rowp[i][r] += e;
                cp += e;
            }
        if (!diag) {
            cp += __shfl_xor(cp, 16, 64);
            cp += __shfl_xor(cp, 32, 64);
            if (ks == 0) atomicAdd(rsB + j * 16 + l15, cp);
        }
    }
    #pragma unroll
    for (int i = 0; i < 4; ++i)
        #pragma unroll
        for (int r = 0; r < 4; ++r) {
            float e = rowp[i][r];
            e += __shfl_xor(e, 1, 64);
            e += __shfl_xor(e, 2, 64);
            e += __shfl_xor(e, 4, 64);
            e += __shfl_xor(e, 8, 64);
            if (l15 == 0) atomicAdd(rsA + i * 16 + ks * 4 + r, e);
        }
}

// ---------------------------------------------------------------------------
// Kernel 3: loss = [ sum_i log(rowsum_i - exp(2*diagss_i)) - 2*sum_k pos_k ] / 8192
// ---------------------------------------------------------------------------
__global__ __launch_bounds__(1024) void finalize_kernel(
    const float* __restrict__ rowsum, const float* __restrict__ diagss,
    const float* __restrict__ pos, float* __restrict__ out)
{
    float local = 0.f;
    for (int i = threadIdx.x; i < M; i += 1024)
        local += __logf(rowsum[i] - __expf(2.0f * diagss[i]));
    for (int k = threadIdx.x; k < N_ROWS; k += 1024)
        local -= 2.0f * pos[k];
    #pragma unroll
    for (int off = 32; off; off >>= 1) local += __shfl_xor(local, off, 64);
    __shared__ float red[16];
    const int wave = threadIdx.x >> 6, lane = threadIdx.x & 63;
    if (lane == 0) red[wave] = local;
    __syncthreads();
    if (threadIdx.x == 0) {
        float t = 0.f;
        #pragma unroll
        for (int w = 0; w < 16; ++w) t += red[w];
        out[0] = t * (1.0f / 8192.0f);
    }
}

// ---------------------------------------------------------------------------
extern "C" void kernel_launch(void* const* d_in, const int* in_sizes, int n_in,
                              void* d_out, int out_size, void* d_ws, size_t ws_size,
                              hipStream_t stream)
{
    const float* emb_i = (const float*)d_in[0];
    const float* emb_j = (const float*)d_in[1];

    // ws layout: zb bf16 [M][D] (8 MB) | rowsum f32[M] | diagss f32[M]
    //            | pos f32[N]   (~8.4 MB total)
    unsigned short* zb = (unsigned short*)d_ws;
    float* rowsum = (float*)((char*)d_ws + (size_t)M * D * sizeof(unsigned short));
    float* diagss = rowsum + M;
    float* pos    = diagss + M;
    float* out    = (float*)d_out;

    normpos_kernel<<<N_ROWS / 4, 256, 0, stream>>>(emb_i, emb_j, zb, rowsum,
                                                   diagss, pos);
    simgemm_kernel<<<NBLK, 256, 0, stream>>>(zb, rowsum);
    finalize_kernel<<<1, 1024, 0, stream>>>(rowsum, diagss, pos, out);
}